// Round 2
// baseline (611.576 us; speedup 1.0000x reference)
//
#include <hip/hip_runtime.h>

#pragma clang fp contract(off)

#define N_PRE   6000
#define N_POST  300
#define NW      94          // 64-bit words per mask row (ceil(6000/64))
#define SORTN   8192

struct SelState {
    unsigned long long prefix;
    unsigned int taken;
    unsigned int pad;
};

// ---------------------------------------------------------------------------
// 1. decode + clip + valid + build sort keys
// key = (sortable_score32 << 32) | ~index  -> distinct; descending score,
// ascending index tie-break == jax.lax.top_k stable order.
// ---------------------------------------------------------------------------
__global__ void decode_kernel(const float4* __restrict__ deltas,
                              const float4* __restrict__ anchors,
                              const float*  __restrict__ scores,
                              const int* __restrict__ ph, const int* __restrict__ pw,
                              const int* __restrict__ ps,
                              unsigned long long* __restrict__ keys,
                              float4* __restrict__ boxes, int N)
{
#pragma clang fp contract(off)
    int i = blockIdx.x * blockDim.x + threadIdx.x;
    if (i >= N) return;
    float H = (float)(*ph), W = (float)(*pw), S = (float)(*ps);
    float4 d = deltas[i];
    float4 a = anchors[i];
    float h = a.z - a.x, w = a.w - a.y;
    float cy = a.x + 0.5f * h, cx = a.y + 0.5f * w;
    float ncy = d.x * h + cy;
    float ncx = d.y * w + cx;
    float eh = (float)exp((double)d.z);   // correctly-rounded f32 exp
    float ew = (float)exp((double)d.w);
    float nh = eh * h;
    float nw = ew * w;
    float ymin = ncy - 0.5f * nh, xmin = ncx - 0.5f * nw;
    float ymax = ncy + 0.5f * nh, xmax = ncx + 0.5f * nw;
    ymin = fminf(fmaxf(ymin, 0.0f), H);
    xmin = fminf(fmaxf(xmin, 0.0f), W);
    ymax = fminf(fmaxf(ymax, 0.0f), H);
    xmax = fminf(fmaxf(xmax, 0.0f), W);
    bool valid = (ymax - ymin >= S) && (xmax - xmin >= S);
    float sc = scores[i];
    unsigned int bits = __float_as_uint(sc);
    unsigned int s32;
    if (!valid) s32 = 0x007FFFFFu;   // sortable encoding of -inf
    else        s32 = (bits & 0x80000000u) ? ~bits : (bits | 0x80000000u);
    keys[i]  = ((unsigned long long)s32 << 32) | (unsigned long long)(~(unsigned int)i);
    boxes[i] = make_float4(ymin, xmin, ymax, xmax);
}

// ---------------------------------------------------------------------------
// 2. radix select (16-bit digits, 4 passes) of the 6000th-largest key
// ---------------------------------------------------------------------------
__global__ void hist_pass(const unsigned long long* __restrict__ keys,
                          const SelState* __restrict__ state,
                          unsigned int* __restrict__ hist, int N, int shift)
{
    int i = blockIdx.x * blockDim.x + threadIdx.x;
    if (i >= N) return;
    unsigned long long key = keys[i];
    if (shift < 48) {
        int hi = shift + 16;
        if ((key >> hi) != (state->prefix >> hi)) return;
    }
    unsigned int digit = (unsigned int)((key >> shift) & 0xFFFFull);
    atomicAdd(&hist[digit], 1u);
}

__global__ __launch_bounds__(1024) void pick_pass(const unsigned int* __restrict__ hist,
                                                  SelState* __restrict__ state, int shift)
{
    __shared__ unsigned int ss[1024];
    __shared__ unsigned int binv[64];
    __shared__ int sel_chunk;
    __shared__ unsigned int sel_acc;
    int tid = threadIdx.x;
    unsigned int k = 6000u - state->taken;

    // per-thread sum over 64 contiguous bins
    unsigned int s = 0;
    int base = tid * 64;
#pragma unroll 8
    for (int i = 0; i < 64; i++) s += hist[base + i];
    ss[tid] = s;
    __syncthreads();
    // inclusive suffix scan over 1024 chunk sums
    for (int d = 1; d < 1024; d <<= 1) {
        unsigned int add = (tid + d < 1024) ? ss[tid + d] : 0u;
        __syncthreads();
        ss[tid] += add;
        __syncthreads();
    }
    unsigned int mine = ss[tid];
    unsigned int nxt  = (tid < 1023) ? ss[tid + 1] : 0u;
    if (nxt < k && k <= mine) { sel_chunk = tid; sel_acc = nxt; }
    __syncthreads();
    int c = sel_chunk;
    unsigned int acc = sel_acc;
    if (tid < 64) binv[tid] = hist[c * 64 + tid];
    __syncthreads();
    // suffix scan over 64 bins (all threads hit barriers)
    for (int d = 1; d < 64; d <<= 1) {
        unsigned int add2 = 0;
        if (tid < 64) add2 = (tid + d < 64) ? binv[tid + d] : 0u;
        __syncthreads();
        if (tid < 64) binv[tid] += add2;
        __syncthreads();
    }
    if (tid < 64) {
        unsigned int m2 = binv[tid];
        unsigned int n2 = (tid < 63) ? binv[tid + 1] : 0u;
        unsigned int kk = k - acc;
        if (n2 < kk && kk <= m2) {
            unsigned long long digit = (unsigned long long)(c * 64 + tid);
            state->prefix |= (digit << shift);
            state->taken  += acc + n2;
        }
    }
}

__global__ void compact_kernel(const unsigned long long* __restrict__ keys,
                               const SelState* __restrict__ state,
                               unsigned long long* __restrict__ sel,
                               unsigned int* __restrict__ counter, int N)
{
    int i = blockIdx.x * blockDim.x + threadIdx.x;
    if (i >= N) return;
    unsigned long long key = keys[i];
    if (key >= state->prefix) {
        unsigned int p = atomicAdd(counter, 1u);
        if (p < N_PRE) sel[p] = key;
    }
}

// ---------------------------------------------------------------------------
// 3. single-block bitonic sort (descending) of 8192 u64 keys + gather
// ---------------------------------------------------------------------------
__global__ __launch_bounds__(1024) void sort_gather(const unsigned long long* __restrict__ sel,
                                                    const unsigned int* __restrict__ counter,
                                                    const float4* __restrict__ boxes,
                                                    float4* __restrict__ boxes_sorted,
                                                    unsigned long long* __restrict__ valid_words,
                                                    int N)
{
    __shared__ unsigned long long smem[SORTN];   // 64 KiB
    int tid = threadIdx.x;
    unsigned int cnt = *counter;
    if (cnt > N_PRE) cnt = N_PRE;
    for (int t = tid; t < SORTN; t += 1024)
        smem[t] = (t < (int)cnt) ? sel[t] : 0ull;   // 0 sorts last (descending)
    __syncthreads();
    for (int k = 2; k <= SORTN; k <<= 1) {
        for (int j = k >> 1; j > 0; j >>= 1) {
            for (int t = tid; t < SORTN; t += 1024) {
                int ixj = t ^ j;
                if (ixj > t) {
                    unsigned long long a = smem[t], b = smem[ixj];
                    bool up = ((t & k) == 0);            // descending sort
                    if (up ? (a < b) : (a > b)) { smem[t] = b; smem[ixj] = a; }
                }
            }
            __syncthreads();
        }
    }
    // gather boxes in sorted order
    for (int t = tid; t < N_PRE; t += 1024) {
        unsigned long long key = smem[t];
        unsigned int ii = ~(unsigned int)(key & 0xFFFFFFFFull);
        boxes_sorted[t] = (ii < (unsigned int)N) ? boxes[ii]
                                                 : make_float4(0.f, 0.f, 0.f, 0.f);
    }
    // valid bitmask via ballot (t ranges are 64-aligned per wave)
    for (int t = tid; t < 6016; t += 1024) {
        bool v = false;
        if (t < N_PRE) {
            unsigned long long key = smem[t];
            unsigned int s32 = (unsigned int)(key >> 32);
            unsigned int ii  = ~(unsigned int)(key & 0xFFFFFFFFull);
            v = (s32 != 0x007FFFFFu) && (ii < (unsigned int)N);
        }
        unsigned long long w = __ballot(v);
        if ((t & 63) == 0) valid_words[t >> 6] = w;
    }
}

// ---------------------------------------------------------------------------
// 4. pairwise suppression mask, upper triangle, one u64 word per (row, cchunk)
// ---------------------------------------------------------------------------
__global__ __launch_bounds__(64) void mask_kernel(const float4* __restrict__ boxes_sorted,
                                                  unsigned long long* __restrict__ mask)
{
#pragma clang fp contract(off)
    int rb = blockIdx.y, cb = blockIdx.x;
    if (cb < rb) return;
    __shared__ float4 cbox[64];
    int tid = threadIdx.x;
    int col0 = cb * 64;
    int c = col0 + tid;
    cbox[tid] = (c < N_PRE) ? boxes_sorted[c] : make_float4(0.f, 0.f, 0.f, 0.f);
    __syncthreads();
    int i = rb * 64 + tid;
    if (i >= N_PRE) return;
    float4 bi = boxes_sorted[i];
    float area_i = (bi.z - bi.x) * (bi.w - bi.y);
    unsigned long long word = 0ull;
    for (int j = 0; j < 64; j++) {
        float4 bj = cbox[j];
        float iy = fminf(bi.z, bj.z) - fmaxf(bi.x, bj.x);
        iy = fmaxf(iy, 0.0f);
        float ix = fminf(bi.w, bj.w) - fmaxf(bi.y, bj.y);
        ix = fmaxf(ix, 0.0f);
        float inter = iy * ix;
        float area_j = (bj.z - bj.x) * (bj.w - bj.y);
        float iou = inter / (((area_i + area_j) - inter) + 1e-9f);
        if ((col0 + j) > i && iou > 0.7f) word |= (1ull << j);
    }
    mask[(size_t)i * NW + cb] = word;
}

// ---------------------------------------------------------------------------
// 5. chunked sequential greedy NMS (single wave), early exit at 300 kept
// ---------------------------------------------------------------------------
__global__ __launch_bounds__(64) void nms_seq(const unsigned long long* __restrict__ mask,
                                              const unsigned long long* __restrict__ valid_words,
                                              const float4* __restrict__ boxes_sorted,
                                              float* __restrict__ out)
{
#pragma clang fp contract(off)
    __shared__ unsigned long long removed[NW];
    __shared__ float4 cbox[64];
    __shared__ unsigned long long cmask[64];
    __shared__ int cand[64];
    __shared__ int klist[64];
    __shared__ int s_cnt, s_next, s_kcnt;
    __shared__ unsigned long long s_alive;

    int lane = threadIdx.x;
    // init: removed = ~valid (invalid boxes pre-removed), pad bits removed
    {
        unsigned long long v = valid_words[lane];
        removed[lane] = ~v;
        int l2 = lane + 64;
        if (l2 < NW) {
            unsigned long long v2 = valid_words[l2];
            if (l2 == NW - 1) v2 &= (1ull << 48) - 1ull;   // 6000 - 93*64 = 48
            removed[l2] = ~v2;
        }
    }
    for (int t = lane; t < N_POST * 4; t += 64) out[t] = 0.0f;
    __syncthreads();

    int rank = 0;
    int start = 0;
    while (rank < N_POST && start < N_PRE) {
        // ---- serial scan for next <=64 alive candidates
        if (lane == 0) {
            int cnt = 0;
            int w = start >> 6;
            unsigned long long cur = removed[w];
            if (start & 63) cur |= (1ull << (start & 63)) - 1ull;
            while (cnt < 64) {
                unsigned long long free_ = ~cur;
                if (free_ == 0ull) {
                    w++;
                    if (w >= NW) break;
                    cur = removed[w];
                    continue;
                }
                int b = __builtin_ctzll(free_);
                cand[cnt++] = w * 64 + b;
                cur |= (1ull << b);
            }
            s_cnt = cnt;
            s_next = (cnt == 64) ? (cand[63] + 1) : N_PRE;
        }
        __syncthreads();
        int cnt = s_cnt;
        if (cnt == 0) break;

        int myidx = (lane < cnt) ? cand[lane] : -1;
        float4 mb = (myidx >= 0) ? boxes_sorted[myidx] : make_float4(0.f, 0.f, 0.f, 0.f);
        cbox[lane] = mb;
        __syncthreads();

        // ---- pairwise IoU among candidates -> suppression bits (j > lane)
        float area_i = (mb.z - mb.x) * (mb.w - mb.y);
        unsigned long long row = 0ull;
        for (int j = 0; j < 64; j++) {
            float4 bj = cbox[j];
            float iy = fminf(mb.z, bj.z) - fmaxf(mb.x, bj.x);
            iy = fmaxf(iy, 0.0f);
            float ix = fminf(mb.w, bj.w) - fmaxf(mb.y, bj.y);
            ix = fmaxf(ix, 0.0f);
            float inter = iy * ix;
            float area_j = (bj.z - bj.x) * (bj.w - bj.y);
            float iou = inter / (((area_i + area_j) - inter) + 1e-9f);
            if (j > lane && iou > 0.7f) row |= (1ull << j);
        }
        cmask[lane] = row;
        __syncthreads();

        // ---- exact greedy resolve within chunk (lane 0, registers)
        if (lane == 0) {
            unsigned long long alive = (cnt >= 64) ? ~0ull : ((1ull << cnt) - 1ull);
            for (int kk = 0; kk < cnt; kk++)
                if ((alive >> kk) & 1ull) alive &= ~cmask[kk];
            s_alive = alive;
            int kc = 0;
            unsigned long long a2 = alive;
            while (a2) {
                int b = __builtin_ctzll(a2);
                a2 &= a2 - 1ull;
                klist[kc++] = cand[b];
            }
            s_kcnt = kc;
        }
        __syncthreads();
        unsigned long long alive = s_alive;
        int kc = s_kcnt;

        // ---- emit kept boxes in rank order
        if (myidx >= 0 && ((alive >> lane) & 1ull)) {
            int pos = rank + __popcll(alive & ((1ull << lane) - 1ull));
            if (pos < N_POST) {
                out[pos * 4 + 0] = mb.x;
                out[pos * 4 + 1] = mb.y;
                out[pos * 4 + 2] = mb.z;
                out[pos * 4 + 3] = mb.w;
            }
        }
        int next = s_next;

        // ---- OR kept rows into removed (register-accumulated, independent loads)
        unsigned long long acc0 = 0ull, acc1 = 0ull;
#pragma unroll 4
        for (int kk = 0; kk < kc; kk++) {
            const unsigned long long* rowp = mask + (size_t)klist[kk] * NW;
            acc0 |= rowp[lane];
            if (lane + 64 < NW) acc1 |= rowp[lane + 64];
        }
        __syncthreads();
        removed[lane] |= acc0;
        if (lane + 64 < NW) removed[lane + 64] |= acc1;
        __syncthreads();

        rank += kc;
        start = next;
    }
}

// ---------------------------------------------------------------------------
extern "C" void kernel_launch(void* const* d_in, const int* in_sizes, int n_in,
                              void* d_out, int out_size, void* d_ws, size_t ws_size,
                              hipStream_t stream)
{
    const float4* deltas  = (const float4*)d_in[0];
    const float4* anchors = (const float4*)d_in[1];
    const float*  scores  = (const float*)d_in[2];
    const int* ph = (const int*)d_in[3];
    const int* pw = (const int*)d_in[4];
    const int* ps = (const int*)d_in[5];
    int N = in_sizes[2];

    char* base = (char*)d_ws;
    size_t off = 0;
    auto alloc = [&](size_t sz) -> void* {
        void* p = base + off;
        off = (off + sz + 255) & ~(size_t)255;
        return p;
    };
    unsigned long long* keys = (unsigned long long*)alloc(sizeof(unsigned long long) * (size_t)N);
    float4* boxes = (float4*)alloc(sizeof(float4) * (size_t)N);
    char* zero_base = base + off;
    unsigned int* hist = (unsigned int*)alloc(4 * 65536 * sizeof(unsigned int));
    SelState* state = (SelState*)alloc(256);
    unsigned int* counter = (unsigned int*)alloc(256);
    unsigned long long* valid_words = (unsigned long long*)alloc(128 * 8);
    unsigned long long* sel = (unsigned long long*)alloc(sizeof(unsigned long long) * 6016);
    size_t zero_sz = (size_t)((base + off) - zero_base);
    float4* boxes_sorted = (float4*)alloc(sizeof(float4) * 6016);
    unsigned long long* mask = (unsigned long long*)alloc(sizeof(unsigned long long) * (size_t)N_PRE * NW);

    hipMemsetAsync(zero_base, 0, zero_sz, stream);
    hipMemsetAsync(mask, 0, sizeof(unsigned long long) * (size_t)N_PRE * NW, stream);

    int nb = (N + 255) / 256;
    decode_kernel<<<nb, 256, 0, stream>>>(deltas, anchors, scores, ph, pw, ps, keys, boxes, N);
    for (int p = 0; p < 4; p++) {
        int shift = 48 - 16 * p;
        hist_pass<<<nb, 256, 0, stream>>>(keys, state, hist + p * 65536, N, shift);
        pick_pass<<<1, 1024, 0, stream>>>(hist + p * 65536, state, shift);
    }
    compact_kernel<<<nb, 256, 0, stream>>>(keys, state, sel, counter, N);
    sort_gather<<<1, 1024, 0, stream>>>(sel, counter, boxes, boxes_sorted, valid_words, N);
    mask_kernel<<<dim3(NW, NW), 64, 0, stream>>>(boxes_sorted, mask);
    nms_seq<<<1, 64, 0, stream>>>(mask, valid_words, boxes_sorted, (float*)d_out);
}

// Round 3
// 600.990 us; speedup vs baseline: 1.0176x; 1.0176x over previous
//
#include <hip/hip_runtime.h>

#pragma clang fp contract(off)

#define N_PRE   6000
#define N_POST  300
#define NW      94          // 64-bit words per mask row (ceil(6000/64))
#define SELPAD  6016        // 94*64

struct SelState {
    unsigned long long prefix;
    unsigned int taken;
    unsigned int pad;
};

// ---------------------------------------------------------------------------
// 1. decode + clip + valid + build sort keys + histogram of top 16 bits
// key = (sortable_score32 << 32) | ~index  -> distinct; descending score,
// ascending index tie-break == jax.lax.top_k stable order.
// ---------------------------------------------------------------------------
__global__ void decode_kernel(const float4* __restrict__ deltas,
                              const float4* __restrict__ anchors,
                              const float*  __restrict__ scores,
                              const int* __restrict__ ph, const int* __restrict__ pw,
                              const int* __restrict__ ps,
                              unsigned long long* __restrict__ keys,
                              float4* __restrict__ boxes,
                              unsigned int* __restrict__ hist0, int N)
{
#pragma clang fp contract(off)
    int i = blockIdx.x * blockDim.x + threadIdx.x;
    if (i >= N) return;
    float H = (float)(*ph), W = (float)(*pw), S = (float)(*ps);
    float4 d = deltas[i];
    float4 a = anchors[i];
    float h = a.z - a.x, w = a.w - a.y;
    float cy = a.x + 0.5f * h, cx = a.y + 0.5f * w;
    float ncy = d.x * h + cy;
    float ncx = d.y * w + cx;
    float eh = (float)exp((double)d.z);   // correctly-rounded f32 exp
    float ew = (float)exp((double)d.w);
    float nh = eh * h;
    float nw = ew * w;
    float ymin = ncy - 0.5f * nh, xmin = ncx - 0.5f * nw;
    float ymax = ncy + 0.5f * nh, xmax = ncx + 0.5f * nw;
    ymin = fminf(fmaxf(ymin, 0.0f), H);
    xmin = fminf(fmaxf(xmin, 0.0f), W);
    ymax = fminf(fmaxf(ymax, 0.0f), H);
    xmax = fminf(fmaxf(xmax, 0.0f), W);
    bool valid = (ymax - ymin >= S) && (xmax - xmin >= S);
    float sc = scores[i];
    unsigned int bits = __float_as_uint(sc);
    unsigned int s32;
    if (!valid) s32 = 0x007FFFFFu;   // sortable encoding of -inf
    else        s32 = (bits & 0x80000000u) ? ~bits : (bits | 0x80000000u);
    keys[i]  = ((unsigned long long)s32 << 32) | (unsigned long long)(~(unsigned int)i);
    boxes[i] = make_float4(ymin, xmin, ymax, xmax);
    atomicAdd(&hist0[s32 >> 16], 1u);
}

// ---------------------------------------------------------------------------
// 2. radix select (16-bit digits, 4 passes) of the 6000th-largest key
// ---------------------------------------------------------------------------
__global__ void hist_pass(const unsigned long long* __restrict__ keys,
                          const SelState* __restrict__ state,
                          unsigned int* __restrict__ hist, int N, int shift)
{
    int i = blockIdx.x * blockDim.x + threadIdx.x;
    if (i >= N) return;
    unsigned long long key = keys[i];
    int hi = shift + 16;
    if ((key >> hi) != (state->prefix >> hi)) return;
    unsigned int digit = (unsigned int)((key >> shift) & 0xFFFFull);
    atomicAdd(&hist[digit], 1u);
}

__global__ __launch_bounds__(1024) void pick_pass(const unsigned int* __restrict__ hist,
                                                  SelState* __restrict__ state, int shift)
{
    __shared__ unsigned int wsum[16];
    __shared__ int sel_chunk;
    __shared__ unsigned int sel_above;
    int tid = threadIdx.x, lane = tid & 63, wave = tid >> 6;
    unsigned int k = 6000u - state->taken;

    unsigned int s = 0;
    int base = tid * 64;
#pragma unroll 8
    for (int i = 0; i < 64; i++) s += hist[base + i];
    // inclusive suffix scan within wave (chunk index = tid, ascending)
    unsigned int S = s;
    for (int d = 1; d < 64; d <<= 1) {
        unsigned int t = __shfl_down(S, d);
        if (lane + d < 64) S += t;
    }
    if (lane == 0) wsum[wave] = S;   // wave total (suffix from its first lane = sum)
    __syncthreads();
    unsigned int above = 0;
    for (int w2 = wave + 1; w2 < 16; w2++) above += wsum[w2];
    unsigned int F  = S + above;   // suffix sum including chunk tid
    unsigned int Fn = F - s;       // suffix sum excluding chunk tid
    if (Fn < k && k <= F) { sel_chunk = tid; sel_above = Fn; }
    __syncthreads();
    int c = sel_chunk;
    unsigned int acc = sel_above;
    if (wave == 0) {
        unsigned int b = hist[c * 64 + lane];
        unsigned int B = b;
        for (int d = 1; d < 64; d <<= 1) {
            unsigned int t = __shfl_down(B, d);
            if (lane + d < 64) B += t;
        }
        unsigned int Bn = B - b;
        unsigned int kk = k - acc;
        if (Bn < kk && kk <= B) {
            state->prefix |= ((unsigned long long)(c * 64 + lane) << shift);
            state->taken  += acc + Bn;
        }
    }
}

__global__ void compact_kernel(const unsigned long long* __restrict__ keys,
                               const SelState* __restrict__ state,
                               unsigned long long* __restrict__ sel,
                               unsigned int* __restrict__ counter, int N)
{
    int i = blockIdx.x * blockDim.x + threadIdx.x;
    if (i >= N) return;
    unsigned long long key = keys[i];
    if (key >= state->prefix) {
        unsigned int p = atomicAdd(counter, 1u);
        if (p < N_PRE) sel[p] = key;
    }
}

// ---------------------------------------------------------------------------
// 3. rank-by-count ordering (replaces bitonic sort): rank = #{greater keys}
//    94 blocks x 256 thr; block owns 64 key slots, 4 slices of 1504 each.
// ---------------------------------------------------------------------------
__global__ __launch_bounds__(256) void rank_scatter(
    const unsigned long long* __restrict__ sel,   // SELPAD entries, zero-padded
    const float4* __restrict__ boxes,
    float4* __restrict__ boxes_sorted,
    unsigned long long* __restrict__ valid_words, int N)
{
    __shared__ unsigned long long kbuf[SELPAD];   // 48.1 KB
    __shared__ unsigned int cnt4[4][64];
    int tid = threadIdx.x;
    for (int t = tid; t < SELPAD; t += 256) kbuf[t] = sel[t];
    __syncthreads();
    int lane = tid & 63;
    int slice = tid >> 6;                 // 0..3
    int i = blockIdx.x * 64 + lane;       // my key slot
    unsigned long long my = kbuf[i];
    int j0 = slice * 1504, j1 = j0 + 1504;
    unsigned int c = 0;
#pragma unroll 8
    for (int j = j0; j < j1; j++) {
        unsigned long long kj = kbuf[j];
        c += (kj > my) || (kj == my && j < i);
    }
    cnt4[slice][lane] = c;
    __syncthreads();
    if (tid < 64) {
        unsigned int rank = cnt4[0][tid] + cnt4[1][tid] + cnt4[2][tid] + cnt4[3][tid];
        int i0 = blockIdx.x * 64 + tid;
        unsigned long long key = kbuf[i0];
        if (rank < N_PRE) {
            unsigned int s32 = (unsigned int)(key >> 32);
            unsigned int ii  = ~(unsigned int)(key & 0xFFFFFFFFull);
            float4 b = (ii < (unsigned int)N) ? boxes[ii] : make_float4(0.f,0.f,0.f,0.f);
            boxes_sorted[rank] = b;
            bool v = (key != 0ull) && (s32 != 0x007FFFFFu) && (ii < (unsigned int)N);
            if (v) atomicOr(&valid_words[rank >> 6], 1ull << (rank & 63));
        }
    }
}

// ---------------------------------------------------------------------------
// 4. pairwise suppression mask, upper triangle, one u64 word per (row, cchunk)
//    lower-triangle words are never written NOR read (guarded in nms_seq).
// ---------------------------------------------------------------------------
__global__ __launch_bounds__(64) void mask_kernel(const float4* __restrict__ boxes_sorted,
                                                  unsigned long long* __restrict__ mask)
{
#pragma clang fp contract(off)
    int rb = blockIdx.y, cb = blockIdx.x;
    if (cb < rb) return;
    __shared__ float4 cbox[64];
    int tid = threadIdx.x;
    int col0 = cb * 64;
    int c = col0 + tid;
    cbox[tid] = (c < N_PRE) ? boxes_sorted[c] : make_float4(0.f, 0.f, 0.f, 0.f);
    __syncthreads();
    int i = rb * 64 + tid;
    if (i >= N_PRE) return;
    float4 bi = boxes_sorted[i];
    float area_i = (bi.z - bi.x) * (bi.w - bi.y);
    unsigned long long word = 0ull;
#pragma unroll 8
    for (int j = 0; j < 64; j++) {
        float4 bj = cbox[j];
        float iy = fminf(bi.z, bj.z) - fmaxf(bi.x, bj.x);
        iy = fmaxf(iy, 0.0f);
        float ix = fminf(bi.w, bj.w) - fmaxf(bi.y, bj.y);
        ix = fmaxf(ix, 0.0f);
        float inter = iy * ix;
        float area_j = (bj.z - bj.x) * (bj.w - bj.y);
        float iou = inter / (((area_i + area_j) - inter) + 1e-9f);
        if ((col0 + j) > i && iou > 0.7f) word |= (1ull << j);
    }
    mask[(size_t)i * NW + cb] = word;
}

// ---------------------------------------------------------------------------
// 5. chunked sequential greedy NMS (single wave), shfl-based resolve
// ---------------------------------------------------------------------------
__global__ __launch_bounds__(64) void nms_seq(const unsigned long long* __restrict__ mask,
                                              const unsigned long long* __restrict__ valid_words,
                                              const float4* __restrict__ boxes_sorted,
                                              float* __restrict__ out)
{
#pragma clang fp contract(off)
    __shared__ unsigned long long removed[NW];
    __shared__ float4 cbox[64];
    __shared__ int cand[64];
    __shared__ int klist[64];
    __shared__ int s_cnt, s_next;

    int lane = threadIdx.x;
    {
        unsigned long long v = valid_words[lane];
        removed[lane] = ~v;
        int l2 = lane + 64;
        if (l2 < NW) {
            unsigned long long v2 = valid_words[l2];
            if (l2 == NW - 1) v2 &= (1ull << 48) - 1ull;   // 6000 - 93*64 = 48
            removed[l2] = ~v2;
        }
    }
    for (int t = lane; t < N_POST * 4; t += 64) out[t] = 0.0f;
    __syncthreads();

    int rank = 0, start = 0;
    while (rank < N_POST && start < N_PRE) {
        // ---- serial scan for next <=64 alive candidates (register ALU loop)
        if (lane == 0) {
            int cnt = 0;
            int w = start >> 6;
            unsigned long long cur = removed[w];
            if (start & 63) cur |= (1ull << (start & 63)) - 1ull;
            while (cnt < 64) {
                unsigned long long free_ = ~cur;
                if (free_ == 0ull) {
                    if (++w >= NW) break;
                    cur = removed[w];
                    continue;
                }
                int b = __builtin_ctzll(free_);
                cand[cnt++] = w * 64 + b;
                cur |= (1ull << b);
            }
            s_cnt = cnt;
            s_next = (cnt == 64) ? (cand[63] + 1) : N_PRE;
        }
        __syncthreads();
        int cnt = s_cnt;
        if (cnt == 0) break;

        int myidx = (lane < cnt) ? cand[lane] : -1;
        float4 mb = (myidx >= 0) ? boxes_sorted[myidx] : make_float4(0.f,0.f,0.f,0.f);
        cbox[lane] = mb;
        __syncthreads();

        // ---- pairwise IoU among candidates -> suppression bits (j > lane)
        float area_i = (mb.z - mb.x) * (mb.w - mb.y);
        unsigned long long row = 0ull;
#pragma unroll 8
        for (int j = 0; j < 64; j++) {
            float4 bj = cbox[j];
            float iy = fminf(mb.z, bj.z) - fmaxf(mb.x, bj.x);
            iy = fmaxf(iy, 0.0f);
            float ix = fminf(mb.w, bj.w) - fmaxf(mb.y, bj.y);
            ix = fmaxf(ix, 0.0f);
            float inter = iy * ix;
            float area_j = (bj.z - bj.x) * (bj.w - bj.y);
            float iou = inter / (((area_i + area_j) - inter) + 1e-9f);
            if (j > lane && iou > 0.7f) row |= (1ull << j);
        }

        // ---- replicated greedy resolve via 64-bit shfl (all lanes, registers)
        unsigned long long alive = (cnt >= 64) ? ~0ull : ((1ull << cnt) - 1ull);
        for (int kk = 0; kk < cnt; kk++) {
            unsigned long long rk = __shfl(row, kk);
            if ((alive >> kk) & 1ull) alive &= ~rk;
        }
        int kc = __popcll(alive);

        // ---- parallel klist build + emit kept boxes in rank order
        if (myidx >= 0 && ((alive >> lane) & 1ull)) {
            int pos = __popcll(alive & ((1ull << lane) - 1ull));
            klist[pos] = myidx;
            int opos = rank + pos;
            if (opos < N_POST) {
                out[opos * 4 + 0] = mb.x;
                out[opos * 4 + 1] = mb.y;
                out[opos * 4 + 2] = mb.z;
                out[opos * 4 + 3] = mb.w;
            }
        }
        __syncthreads();

        // ---- OR kept rows into removed (pipelined, triangular guard)
        unsigned long long acc0 = 0ull, acc1 = 0ull;
#pragma unroll 4
        for (int kk = 0; kk < kc; kk++) {
            int r = klist[kk];
            const unsigned long long* rowp = mask + (size_t)r * NW;
            int rb = r >> 6;
            if (lane >= rb) acc0 |= rowp[lane];
            int l2 = lane + 64;
            if (l2 < NW && l2 >= rb) acc1 |= rowp[l2];
        }
        removed[lane] |= acc0;
        if (lane + 64 < NW) removed[lane + 64] |= acc1;
        __syncthreads();

        rank += kc;
        start = s_next;
    }
}

// ---------------------------------------------------------------------------
extern "C" void kernel_launch(void* const* d_in, const int* in_sizes, int n_in,
                              void* d_out, int out_size, void* d_ws, size_t ws_size,
                              hipStream_t stream)
{
    const float4* deltas  = (const float4*)d_in[0];
    const float4* anchors = (const float4*)d_in[1];
    const float*  scores  = (const float*)d_in[2];
    const int* ph = (const int*)d_in[3];
    const int* pw = (const int*)d_in[4];
    const int* ps = (const int*)d_in[5];
    int N = in_sizes[2];

    char* base = (char*)d_ws;
    size_t off = 0;
    auto alloc = [&](size_t sz) -> void* {
        void* p = base + off;
        off = (off + sz + 255) & ~(size_t)255;
        return p;
    };
    unsigned long long* keys = (unsigned long long*)alloc(sizeof(unsigned long long) * (size_t)N);
    float4* boxes = (float4*)alloc(sizeof(float4) * (size_t)N);
    char* zero_base = base + off;
    unsigned int* hist = (unsigned int*)alloc(4 * 65536 * sizeof(unsigned int));
    SelState* state = (SelState*)alloc(256);
    unsigned int* counter = (unsigned int*)alloc(256);
    unsigned long long* valid_words = (unsigned long long*)alloc(128 * 8);
    unsigned long long* sel = (unsigned long long*)alloc(sizeof(unsigned long long) * SELPAD);
    float4* boxes_sorted = (float4*)alloc(sizeof(float4) * SELPAD);
    size_t zero_sz = (size_t)((base + off) - zero_base);
    unsigned long long* mask = (unsigned long long*)alloc(sizeof(unsigned long long) * (size_t)N_PRE * NW);

    hipMemsetAsync(zero_base, 0, zero_sz, stream);

    int nb = (N + 255) / 256;
    decode_kernel<<<nb, 256, 0, stream>>>(deltas, anchors, scores, ph, pw, ps,
                                          keys, boxes, hist, N);
    pick_pass<<<1, 1024, 0, stream>>>(hist, state, 48);
    for (int p = 1; p < 4; p++) {
        int shift = 48 - 16 * p;
        hist_pass<<<nb, 256, 0, stream>>>(keys, state, hist + p * 65536, N, shift);
        pick_pass<<<1, 1024, 0, stream>>>(hist + p * 65536, state, shift);
    }
    compact_kernel<<<nb, 256, 0, stream>>>(keys, state, sel, counter, N);
    rank_scatter<<<94, 256, 0, stream>>>(sel, boxes, boxes_sorted, valid_words, N);
    mask_kernel<<<dim3(NW, NW), 64, 0, stream>>>(boxes_sorted, mask);
    nms_seq<<<1, 64, 0, stream>>>(mask, valid_words, boxes_sorted, (float*)d_out);
}

// Round 4
// 565.525 us; speedup vs baseline: 1.0814x; 1.0627x over previous
//
#include <hip/hip_runtime.h>

#pragma clang fp contract(off)

#define N_PRE   6000
#define N_POST  300
#define NW      94          // 64-bit words per mask row (ceil(6000/64))
#define SELCAP  7936        // 124*64 pool capacity (top-6000 + 16-bit-bucket ties)
#define RS_BLK  124

struct SelState {
    unsigned int thr;       // 16-bit digit threshold: keep if (s32>>16) >= thr
};

// ---------------------------------------------------------------------------
// 1. decode + clip + valid + sortable 32-bit score key + 16-bit-top histogram
// full key (built later) = (s32 << 32) | ~index  -> distinct; descending
// score, ascending index tie-break == jax.lax.top_k stable order.
// ---------------------------------------------------------------------------
__global__ void decode_kernel(const float4* __restrict__ deltas,
                              const float4* __restrict__ anchors,
                              const float*  __restrict__ scores,
                              const int* __restrict__ ph, const int* __restrict__ pw,
                              const int* __restrict__ ps,
                              unsigned int* __restrict__ s32out,
                              float4* __restrict__ boxes,
                              unsigned int* __restrict__ hist0, int N)
{
#pragma clang fp contract(off)
    int i = blockIdx.x * blockDim.x + threadIdx.x;
    if (i >= N) return;
    float H = (float)(*ph), W = (float)(*pw), S = (float)(*ps);
    float4 d = deltas[i];
    float4 a = anchors[i];
    float h = a.z - a.x, w = a.w - a.y;
    float cy = a.x + 0.5f * h, cx = a.y + 0.5f * w;
    float ncy = d.x * h + cy;
    float ncx = d.y * w + cx;
    float eh = (float)exp((double)d.z);   // correctly-rounded f32 exp
    float ew = (float)exp((double)d.w);
    float nh = eh * h;
    float nw = ew * w;
    float ymin = ncy - 0.5f * nh, xmin = ncx - 0.5f * nw;
    float ymax = ncy + 0.5f * nh, xmax = ncx + 0.5f * nw;
    ymin = fminf(fmaxf(ymin, 0.0f), H);
    xmin = fminf(fmaxf(xmin, 0.0f), W);
    ymax = fminf(fmaxf(ymax, 0.0f), H);
    xmax = fminf(fmaxf(xmax, 0.0f), W);
    bool valid = (ymax - ymin >= S) && (xmax - xmin >= S);
    float sc = scores[i];
    unsigned int bits = __float_as_uint(sc);
    unsigned int s32;
    if (!valid) s32 = 0x007FFFFFu;   // sortable encoding of -inf
    else        s32 = (bits & 0x80000000u) ? ~bits : (bits | 0x80000000u);
    s32out[i] = s32;
    boxes[i]  = make_float4(ymin, xmin, ymax, xmax);
    atomicAdd(&hist0[s32 >> 16], 1u);
}

// ---------------------------------------------------------------------------
// 2. pick: d0 = max 16-bit digit with suffix-count(>= d0) >= 6000
// ---------------------------------------------------------------------------
__global__ __launch_bounds__(1024) void pick_pass(const unsigned int* __restrict__ hist,
                                                  SelState* __restrict__ state)
{
    __shared__ unsigned int wsum[16];
    int tid = threadIdx.x, lane = tid & 63, wave = tid >> 6;
    const unsigned int k = 6000u;

    unsigned int s = 0;
    int base = tid * 64;
#pragma unroll 8
    for (int i = 0; i < 64; i++) s += hist[base + i];
    // inclusive suffix scan within wave (chunk index ascending)
    unsigned int S = s;
    for (int d = 1; d < 64; d <<= 1) {
        unsigned int t = __shfl_down(S, d);
        if (lane + d < 64) S += t;
    }
    if (lane == 0) wsum[wave] = S;
    __syncthreads();
    unsigned int above = 0;
    for (int w2 = wave + 1; w2 < 16; w2++) above += wsum[w2];
    unsigned int F  = S + above;   // suffix including chunk tid
    unsigned int Fn = F - s;       // suffix excluding chunk tid
    __shared__ int sel_chunk;
    __shared__ unsigned int sel_above;
    if (Fn < k && k <= F) { sel_chunk = tid; sel_above = Fn; }
    __syncthreads();
    int c = sel_chunk;
    unsigned int acc = sel_above;
    if (wave == 0) {
        unsigned int b = hist[c * 64 + lane];
        unsigned int B = b;
        for (int d = 1; d < 64; d <<= 1) {
            unsigned int t = __shfl_down(B, d);
            if (lane + d < 64) B += t;
        }
        unsigned int Bn = B - b;
        unsigned int kk = k - acc;
        if (Bn < kk && kk <= B) state->thr = (unsigned int)(c * 64 + lane);
    }
}

// ---------------------------------------------------------------------------
// 3. compact: pool = all elements whose top-16 digit >= thr (>= 6000, <= cap)
// ---------------------------------------------------------------------------
__global__ void compact_kernel(const unsigned int* __restrict__ s32in,
                               const SelState* __restrict__ state,
                               unsigned long long* __restrict__ sel,
                               unsigned int* __restrict__ counter, int N)
{
    int i = blockIdx.x * blockDim.x + threadIdx.x;
    if (i >= N) return;
    unsigned int s32 = s32in[i];
    if ((s32 >> 16) >= state->thr) {
        unsigned int p = atomicAdd(counter, 1u);
        if (p < SELCAP)
            sel[p] = ((unsigned long long)s32 << 32) |
                     (unsigned long long)(~(unsigned int)i);
    }
}

// ---------------------------------------------------------------------------
// 4. exact rank by count over full 64-bit keys; scatter boxes + valid bits
// ---------------------------------------------------------------------------
__global__ __launch_bounds__(256) void rank_scatter(
    const unsigned long long* __restrict__ sel,   // SELCAP entries, zero-padded
    const float4* __restrict__ boxes,
    float4* __restrict__ boxes_sorted,
    unsigned long long* __restrict__ valid_words, int N)
{
    __shared__ __align__(16) unsigned long long kbuf[SELCAP];   // 62 KiB
    __shared__ unsigned int cnt4[4][64];
    int tid = threadIdx.x;
    for (int t = tid; t < SELCAP; t += 256) kbuf[t] = sel[t];
    __syncthreads();
    int lane = tid & 63;
    int slice = tid >> 6;                 // 0..3
    int i = blockIdx.x * 64 + lane;       // my key slot
    unsigned long long my = kbuf[i];
    const int SL = SELCAP / 4;            // 1984
    int j0 = slice * SL;
    unsigned int c = 0;
#pragma unroll 8
    for (int j = j0; j < j0 + SL; j += 2) {
        ulonglong2 kk = *reinterpret_cast<const ulonglong2*>(&kbuf[j]);
        c += (kk.x > my) || (kk.x == my && j < i);
        c += (kk.y > my) || (kk.y == my && (j + 1) < i);
    }
    cnt4[slice][lane] = c;
    __syncthreads();
    if (tid < 64) {
        unsigned int rank = cnt4[0][tid] + cnt4[1][tid] + cnt4[2][tid] + cnt4[3][tid];
        unsigned long long key = kbuf[blockIdx.x * 64 + tid];
        if (key != 0ull && rank < N_PRE) {
            unsigned int s32 = (unsigned int)(key >> 32);
            unsigned int ii  = ~(unsigned int)(key & 0xFFFFFFFFull);
            float4 b = (ii < (unsigned int)N) ? boxes[ii] : make_float4(0.f,0.f,0.f,0.f);
            boxes_sorted[rank] = b;
            bool v = (s32 != 0x007FFFFFu) && (ii < (unsigned int)N);
            if (v) atomicOr(&valid_words[rank >> 6], 1ull << (rank & 63));
        }
    }
}

// ---------------------------------------------------------------------------
// 5. pairwise suppression mask, upper triangle only
// ---------------------------------------------------------------------------
__global__ __launch_bounds__(64) void mask_kernel(const float4* __restrict__ boxes_sorted,
                                                  unsigned long long* __restrict__ mask)
{
#pragma clang fp contract(off)
    int rb = blockIdx.y, cb = blockIdx.x;
    if (cb < rb) return;
    __shared__ float4 cbox[64];
    int tid = threadIdx.x;
    int col0 = cb * 64;
    int c = col0 + tid;
    cbox[tid] = (c < N_PRE) ? boxes_sorted[c] : make_float4(0.f, 0.f, 0.f, 0.f);
    __syncthreads();
    int i = rb * 64 + tid;
    if (i >= N_PRE) return;
    float4 bi = boxes_sorted[i];
    float area_i = (bi.z - bi.x) * (bi.w - bi.y);
    unsigned long long word = 0ull;
#pragma unroll 8
    for (int j = 0; j < 64; j++) {
        float4 bj = cbox[j];
        float iy = fminf(bi.z, bj.z) - fmaxf(bi.x, bj.x);
        iy = fmaxf(iy, 0.0f);
        float ix = fminf(bi.w, bj.w) - fmaxf(bi.y, bj.y);
        ix = fmaxf(ix, 0.0f);
        float inter = iy * ix;
        float area_j = (bj.z - bj.x) * (bj.w - bj.y);
        float iou = inter / (((area_i + area_j) - inter) + 1e-9f);
        if ((col0 + j) > i && iou > 0.7f) word |= (1ull << j);
    }
    mask[(size_t)i * NW + cb] = word;
}

// ---------------------------------------------------------------------------
// 6. chunked sequential greedy NMS, on-demand in-chunk resolve:
//    only KEPT candidates (~6/chunk) trigger work (1 IoU per lane + ballot).
// ---------------------------------------------------------------------------
__global__ __launch_bounds__(64) void nms_seq(const unsigned long long* __restrict__ mask,
                                              const unsigned long long* __restrict__ valid_words,
                                              const float4* __restrict__ boxes_sorted,
                                              float* __restrict__ out)
{
#pragma clang fp contract(off)
    __shared__ unsigned long long removed[NW];
    __shared__ int cand[64];
    __shared__ int klist[64];
    __shared__ int s_cnt, s_next;

    int lane = threadIdx.x;
    {
        unsigned long long v = valid_words[lane];
        removed[lane] = ~v;
        int l2 = lane + 64;
        if (l2 < NW) {
            unsigned long long v2 = valid_words[l2];
            if (l2 == NW - 1) v2 &= (1ull << 48) - 1ull;   // 6000 - 93*64 = 48
            removed[l2] = ~v2;
        }
    }
    for (int t = lane; t < N_POST * 4; t += 64) out[t] = 0.0f;
    __syncthreads();

    int rank = 0, start = 0;
    while (rank < N_POST && start < N_PRE) {
        // ---- serial scan for next <=64 alive candidates
        if (lane == 0) {
            int cnt = 0;
            int w = start >> 6;
            unsigned long long cur = removed[w];
            if (start & 63) cur |= (1ull << (start & 63)) - 1ull;
            while (cnt < 64) {
                unsigned long long free_ = ~cur;
                if (free_ == 0ull) {
                    if (++w >= NW) break;
                    cur = removed[w];
                    continue;
                }
                int b = __builtin_ctzll(free_);
                cand[cnt++] = w * 64 + b;
                cur |= (1ull << b);
            }
            s_cnt = cnt;
            s_next = (cnt == 64) ? (cand[63] + 1) : N_PRE;
        }
        __syncthreads();
        int cnt = s_cnt;
        if (cnt == 0) break;

        int myidx = (lane < cnt) ? cand[lane] : -1;
        float4 mb = (myidx >= 0) ? boxes_sorted[myidx] : make_float4(0.f,0.f,0.f,0.f);
        float area_i = (mb.z - mb.x) * (mb.w - mb.y);

        // ---- on-demand greedy resolve: process only surviving candidates
        unsigned long long pend  = (cnt >= 64) ? ~0ull : ((1ull << cnt) - 1ull);
        unsigned long long keptm = 0ull;
        while (pend) {
            int b = __builtin_ctzll(pend);      // wave-uniform
            keptm |= (1ull << b);
            float bx = __shfl(mb.x, b);
            float by = __shfl(mb.y, b);
            float bz = __shfl(mb.z, b);
            float bw = __shfl(mb.w, b);
            float iy = fmaxf(fminf(mb.z, bz) - fmaxf(mb.x, bx), 0.0f);
            float ix = fmaxf(fminf(mb.w, bw) - fmaxf(mb.y, by), 0.0f);
            float inter = iy * ix;
            float area_b = (bz - bx) * (bw - by);
            float iou = inter / (((area_i + area_b) - inter) + 1e-9f);
            unsigned long long sup = __ballot(iou > 0.7f);
            pend &= ~sup;
            pend &= ~(1ull << b);
        }
        int kc = __popcll(keptm);

        // ---- emit kept boxes in rank order + build klist
        if (myidx >= 0 && ((keptm >> lane) & 1ull)) {
            int pos = __popcll(keptm & ((1ull << lane) - 1ull));
            klist[pos] = myidx;
            int opos = rank + pos;
            if (opos < N_POST)
                *reinterpret_cast<float4*>(&out[opos * 4]) = mb;
        }
        __syncthreads();

        // ---- OR kept rows into removed (upper-triangle words only)
        unsigned long long acc0 = 0ull, acc1 = 0ull;
        for (int kk = 0; kk < kc; kk++) {
            int r = klist[kk];
            const unsigned long long* rowp = mask + (size_t)r * NW;
            int rw = r >> 6;
            if (lane >= rw) acc0 |= rowp[lane];
            int l2 = lane + 64;
            if (l2 < NW && l2 >= rw) acc1 |= rowp[l2];
        }
        removed[lane] |= acc0;
        if (lane + 64 < NW) removed[lane + 64] |= acc1;
        __syncthreads();

        rank += kc;
        start = s_next;
    }
}

// ---------------------------------------------------------------------------
extern "C" void kernel_launch(void* const* d_in, const int* in_sizes, int n_in,
                              void* d_out, int out_size, void* d_ws, size_t ws_size,
                              hipStream_t stream)
{
    const float4* deltas  = (const float4*)d_in[0];
    const float4* anchors = (const float4*)d_in[1];
    const float*  scores  = (const float*)d_in[2];
    const int* ph = (const int*)d_in[3];
    const int* pw = (const int*)d_in[4];
    const int* ps = (const int*)d_in[5];
    int N = in_sizes[2];

    char* base = (char*)d_ws;
    size_t off = 0;
    auto alloc = [&](size_t sz) -> void* {
        void* p = base + off;
        off = (off + sz + 255) & ~(size_t)255;
        return p;
    };
    unsigned int* s32buf = (unsigned int*)alloc(sizeof(unsigned int) * (size_t)N);
    float4* boxes = (float4*)alloc(sizeof(float4) * (size_t)N);
    char* zero_base = base + off;
    unsigned int* hist = (unsigned int*)alloc(65536 * sizeof(unsigned int));
    SelState* state = (SelState*)alloc(256);
    unsigned int* counter = (unsigned int*)alloc(256);
    unsigned long long* valid_words = (unsigned long long*)alloc(128 * 8);
    unsigned long long* sel = (unsigned long long*)alloc(sizeof(unsigned long long) * SELCAP);
    size_t zero_sz = (size_t)((base + off) - zero_base);
    float4* boxes_sorted = (float4*)alloc(sizeof(float4) * 6016);
    unsigned long long* mask = (unsigned long long*)alloc(sizeof(unsigned long long) * (size_t)N_PRE * NW);

    hipMemsetAsync(zero_base, 0, zero_sz, stream);

    int nb = (N + 255) / 256;
    decode_kernel<<<nb, 256, 0, stream>>>(deltas, anchors, scores, ph, pw, ps,
                                          s32buf, boxes, hist, N);
    pick_pass<<<1, 1024, 0, stream>>>(hist, state);
    compact_kernel<<<nb, 256, 0, stream>>>(s32buf, state, sel, counter, N);
    rank_scatter<<<RS_BLK, 256, 0, stream>>>(sel, boxes, boxes_sorted, valid_words, N);
    mask_kernel<<<dim3(NW, NW), 64, 0, stream>>>(boxes_sorted, mask);
    nms_seq<<<1, 64, 0, stream>>>(mask, valid_words, boxes_sorted, (float*)d_out);
}

// Round 5
// 398.393 us; speedup vs baseline: 1.5351x; 1.4195x over previous
//
#include <hip/hip_runtime.h>

#pragma clang fp contract(off)

#define N_PRE   6000
#define N_POST  300
#define NW      94          // 64-bit words per mask row (ceil(6000/64))
#define SELCAP  7936        // 124*64 pool capacity (top-6000 + 16-bit-bucket ties)
#define RS_BLK  124

struct SelState {
    unsigned int thr;       // 16-bit digit threshold: keep if (s32>>16) >= thr
};

// ---------------------------------------------------------------------------
// 1. decode + clip + valid + sortable 32-bit score key + 16-bit-top histogram
// full key (built later) = (s32 << 32) | ~index  -> distinct; descending
// score, ascending index tie-break == jax.lax.top_k stable order.
// ---------------------------------------------------------------------------
__global__ void decode_kernel(const float4* __restrict__ deltas,
                              const float4* __restrict__ anchors,
                              const float*  __restrict__ scores,
                              const int* __restrict__ ph, const int* __restrict__ pw,
                              const int* __restrict__ ps,
                              unsigned int* __restrict__ s32out,
                              float4* __restrict__ boxes,
                              unsigned int* __restrict__ hist0, int N)
{
#pragma clang fp contract(off)
    int i = blockIdx.x * blockDim.x + threadIdx.x;
    if (i >= N) return;
    float H = (float)(*ph), W = (float)(*pw), S = (float)(*ps);
    float4 d = deltas[i];
    float4 a = anchors[i];
    float h = a.z - a.x, w = a.w - a.y;
    float cy = a.x + 0.5f * h, cx = a.y + 0.5f * w;
    float ncy = d.x * h + cy;
    float ncx = d.y * w + cx;
    float eh = (float)exp((double)d.z);   // correctly-rounded f32 exp
    float ew = (float)exp((double)d.w);
    float nh = eh * h;
    float nw = ew * w;
    float ymin = ncy - 0.5f * nh, xmin = ncx - 0.5f * nw;
    float ymax = ncy + 0.5f * nh, xmax = ncx + 0.5f * nw;
    ymin = fminf(fmaxf(ymin, 0.0f), H);
    xmin = fminf(fmaxf(xmin, 0.0f), W);
    ymax = fminf(fmaxf(ymax, 0.0f), H);
    xmax = fminf(fmaxf(xmax, 0.0f), W);
    bool valid = (ymax - ymin >= S) && (xmax - xmin >= S);
    float sc = scores[i];
    unsigned int bits = __float_as_uint(sc);
    unsigned int s32;
    if (!valid) s32 = 0x007FFFFFu;   // sortable encoding of -inf
    else        s32 = (bits & 0x80000000u) ? ~bits : (bits | 0x80000000u);
    s32out[i] = s32;
    boxes[i]  = make_float4(ymin, xmin, ymax, xmax);
    atomicAdd(&hist0[s32 >> 16], 1u);
}

// ---------------------------------------------------------------------------
// 2. pick: thr = max 16-bit digit with suffix-count(>= thr) >= 6000
// ---------------------------------------------------------------------------
__global__ __launch_bounds__(1024) void pick_pass(const unsigned int* __restrict__ hist,
                                                  SelState* __restrict__ state)
{
    __shared__ unsigned int wsum[16];
    int tid = threadIdx.x, lane = tid & 63, wave = tid >> 6;
    const unsigned int k = 6000u;

    unsigned int s = 0;
    int base = tid * 64;
#pragma unroll 8
    for (int i = 0; i < 64; i++) s += hist[base + i];
    unsigned int S = s;
    for (int d = 1; d < 64; d <<= 1) {
        unsigned int t = __shfl_down(S, d);
        if (lane + d < 64) S += t;
    }
    if (lane == 0) wsum[wave] = S;
    __syncthreads();
    unsigned int above = 0;
    for (int w2 = wave + 1; w2 < 16; w2++) above += wsum[w2];
    unsigned int F  = S + above;
    unsigned int Fn = F - s;
    __shared__ int sel_chunk;
    __shared__ unsigned int sel_above;
    if (Fn < k && k <= F) { sel_chunk = tid; sel_above = Fn; }
    __syncthreads();
    int c = sel_chunk;
    unsigned int acc = sel_above;
    if (wave == 0) {
        unsigned int b = hist[c * 64 + lane];
        unsigned int B = b;
        for (int d = 1; d < 64; d <<= 1) {
            unsigned int t = __shfl_down(B, d);
            if (lane + d < 64) B += t;
        }
        unsigned int Bn = B - b;
        unsigned int kk = k - acc;
        if (Bn < kk && kk <= B) state->thr = (unsigned int)(c * 64 + lane);
    }
}

// ---------------------------------------------------------------------------
// 3. compact: pool = all elements whose top-16 digit >= thr (>= 6000, <= cap)
// ---------------------------------------------------------------------------
__global__ void compact_kernel(const unsigned int* __restrict__ s32in,
                               const SelState* __restrict__ state,
                               unsigned long long* __restrict__ sel,
                               unsigned int* __restrict__ counter, int N)
{
    int i = blockIdx.x * blockDim.x + threadIdx.x;
    if (i >= N) return;
    unsigned int s32 = s32in[i];
    if ((s32 >> 16) >= state->thr) {
        unsigned int p = atomicAdd(counter, 1u);
        if (p < SELCAP)
            sel[p] = ((unsigned long long)s32 << 32) |
                     (unsigned long long)(~(unsigned int)i);
    }
}

// ---------------------------------------------------------------------------
// 4. exact rank by count over full 64-bit keys; scatter boxes + valid bits
// ---------------------------------------------------------------------------
__global__ __launch_bounds__(256) void rank_scatter(
    const unsigned long long* __restrict__ sel,   // SELCAP entries, zero-padded
    const float4* __restrict__ boxes,
    float4* __restrict__ boxes_sorted,
    unsigned long long* __restrict__ valid_words, int N)
{
    __shared__ __align__(16) unsigned long long kbuf[SELCAP];   // 62 KiB
    __shared__ unsigned int cnt4[4][64];
    int tid = threadIdx.x;
    for (int t = tid; t < SELCAP; t += 256) kbuf[t] = sel[t];
    __syncthreads();
    int lane = tid & 63;
    int slice = tid >> 6;                 // 0..3
    int i = blockIdx.x * 64 + lane;       // my key slot
    unsigned long long my = kbuf[i];
    const int SL = SELCAP / 4;            // 1984
    int j0 = slice * SL;
    unsigned int c = 0;
#pragma unroll 8
    for (int j = j0; j < j0 + SL; j += 2) {
        ulonglong2 kk = *reinterpret_cast<const ulonglong2*>(&kbuf[j]);
        c += (kk.x > my) || (kk.x == my && j < i);
        c += (kk.y > my) || (kk.y == my && (j + 1) < i);
    }
    cnt4[slice][lane] = c;
    __syncthreads();
    if (tid < 64) {
        unsigned int rank = cnt4[0][tid] + cnt4[1][tid] + cnt4[2][tid] + cnt4[3][tid];
        unsigned long long key = kbuf[blockIdx.x * 64 + tid];
        if (key != 0ull && rank < N_PRE) {
            unsigned int s32 = (unsigned int)(key >> 32);
            unsigned int ii  = ~(unsigned int)(key & 0xFFFFFFFFull);
            float4 b = (ii < (unsigned int)N) ? boxes[ii] : make_float4(0.f,0.f,0.f,0.f);
            boxes_sorted[rank] = b;
            bool v = (s32 != 0x007FFFFFu) && (ii < (unsigned int)N);
            if (v) atomicOr(&valid_words[rank >> 6], 1ull << (rank & 63));
        }
    }
}

// ---------------------------------------------------------------------------
// 5. pairwise suppression mask, upper triangle only (incl. diagonal word)
// ---------------------------------------------------------------------------
__global__ __launch_bounds__(64) void mask_kernel(const float4* __restrict__ boxes_sorted,
                                                  unsigned long long* __restrict__ mask)
{
#pragma clang fp contract(off)
    int rb = blockIdx.y, cb = blockIdx.x;
    if (cb < rb) return;
    __shared__ float4 cbox[64];
    int tid = threadIdx.x;
    int col0 = cb * 64;
    int c = col0 + tid;
    cbox[tid] = (c < N_PRE) ? boxes_sorted[c] : make_float4(0.f, 0.f, 0.f, 0.f);
    __syncthreads();
    int i = rb * 64 + tid;
    if (i >= N_PRE) return;
    float4 bi = boxes_sorted[i];
    float area_i = (bi.z - bi.x) * (bi.w - bi.y);
    unsigned long long word = 0ull;
#pragma unroll 8
    for (int j = 0; j < 64; j++) {
        float4 bj = cbox[j];
        float iy = fminf(bi.z, bj.z) - fmaxf(bi.x, bj.x);
        iy = fmaxf(iy, 0.0f);
        float ix = fminf(bi.w, bj.w) - fmaxf(bi.y, bj.y);
        ix = fmaxf(ix, 0.0f);
        float inter = iy * ix;
        float area_j = (bj.z - bj.x) * (bj.w - bj.y);
        float iou = inter / (((area_i + area_j) - inter) + 1e-9f);
        if ((col0 + j) > i && iou > 0.7f) word |= (1ull << j);
    }
    mask[(size_t)i * NW + cb] = word;
}

// ---------------------------------------------------------------------------
// 6. word-sequential greedy NMS, single wave, zero LDS:
//    removed[] words live in registers (lane l owns word l and word 64+l),
//    current word broadcast via shfl; keeps resolved by ballot-IoU;
//    mask-row ORs batched 4-wide so each word pays ~one memory latency.
// ---------------------------------------------------------------------------
__global__ __launch_bounds__(64) void nms_seq(const unsigned long long* __restrict__ mask,
                                              const unsigned long long* __restrict__ valid_words,
                                              const float4* __restrict__ boxes_sorted,
                                              float* __restrict__ out)
{
#pragma clang fp contract(off)
    int lane = threadIdx.x;
    float4* out4 = reinterpret_cast<float4*>(out);

    // zero output
    for (int t = lane; t < N_POST; t += 64)
        out4[t] = make_float4(0.f, 0.f, 0.f, 0.f);

    // removed-words in registers; pad bits of word 93 are 0 in valid_words
    unsigned long long rem0 = ~valid_words[lane];
    unsigned long long rem1 = ~((lane < NW - 64) ? valid_words[64 + lane] : 0ull);

    int rank = 0;
    float4 cb = boxes_sorted[lane];          // word 0 boxes
    for (int w = 0; w < NW; w++) {
        // prefetch next word's boxes
        float4 nb;
        if (w < NW - 1) nb = boxes_sorted[(w + 1) * 64 + lane];

        // broadcast removed word w from its owner lane
        unsigned long long remw = (w < 64) ? __shfl(rem0, w) : __shfl(rem1, w - 64);
        unsigned long long aw = ~remw;

        unsigned long long keptb = 0ull;
        if (aw) {
            float area_me = (cb.z - cb.x) * (cb.w - cb.y);
            while (aw) {
                int b = __builtin_ctzll(aw);     // wave-uniform
                float kx = __shfl(cb.x, b);
                float ky = __shfl(cb.y, b);
                float kz = __shfl(cb.z, b);
                float kw = __shfl(cb.w, b);
                float iy = fmaxf(fminf(cb.z, kz) - fmaxf(cb.x, kx), 0.0f);
                float ix = fmaxf(fminf(cb.w, kw) - fmaxf(cb.y, ky), 0.0f);
                float inter = iy * ix;
                float ka = (kz - kx) * (kw - ky);
                float iou = inter / (((area_me + ka) - inter) + 1e-9f);
                unsigned long long sup = __ballot(iou > 0.7f);
                if (lane == b) out4[rank] = cb;
                keptb |= (1ull << b);
                rank++;
                aw &= ~(sup | (1ull << b));
                if (rank >= N_POST) break;
            }
        }

        if (rank >= N_POST) break;

        // apply mask rows of this word's keeps (4-wide independent loads)
        unsigned long long kb = keptb;
        while (kb) {
            int b0 = __builtin_ctzll(kb); kb &= kb - 1ull;
            int b1 = -1, b2 = -1, b3 = -1;
            if (kb) { b1 = __builtin_ctzll(kb); kb &= kb - 1ull; }
            if (kb) { b2 = __builtin_ctzll(kb); kb &= kb - 1ull; }
            if (kb) { b3 = __builtin_ctzll(kb); kb &= kb - 1ull; }
            const unsigned long long* p0 = mask + (size_t)(w * 64 + b0) * NW;
            unsigned long long l0 = p0[lane];
            unsigned long long h0 = (lane < NW - 64) ? p0[64 + lane] : 0ull;
            unsigned long long l1 = 0, h1 = 0, l2 = 0, h2 = 0, l3 = 0, h3 = 0;
            if (b1 >= 0) {
                const unsigned long long* p1 = mask + (size_t)(w * 64 + b1) * NW;
                l1 = p1[lane];
                h1 = (lane < NW - 64) ? p1[64 + lane] : 0ull;
            }
            if (b2 >= 0) {
                const unsigned long long* p2 = mask + (size_t)(w * 64 + b2) * NW;
                l2 = p2[lane];
                h2 = (lane < NW - 64) ? p2[64 + lane] : 0ull;
            }
            if (b3 >= 0) {
                const unsigned long long* p3 = mask + (size_t)(w * 64 + b3) * NW;
                l3 = p3[lane];
                h3 = (lane < NW - 64) ? p3[64 + lane] : 0ull;
            }
            // garbage in words < w is harmless: those words are never revisited
            rem0 |= (l0 | l1) | (l2 | l3);
            rem1 |= (h0 | h1) | (h2 | h3);
        }

        cb = nb;
    }
}

// ---------------------------------------------------------------------------
extern "C" void kernel_launch(void* const* d_in, const int* in_sizes, int n_in,
                              void* d_out, int out_size, void* d_ws, size_t ws_size,
                              hipStream_t stream)
{
    const float4* deltas  = (const float4*)d_in[0];
    const float4* anchors = (const float4*)d_in[1];
    const float*  scores  = (const float*)d_in[2];
    const int* ph = (const int*)d_in[3];
    const int* pw = (const int*)d_in[4];
    const int* ps = (const int*)d_in[5];
    int N = in_sizes[2];

    char* base = (char*)d_ws;
    size_t off = 0;
    auto alloc = [&](size_t sz) -> void* {
        void* p = base + off;
        off = (off + sz + 255) & ~(size_t)255;
        return p;
    };
    unsigned int* s32buf = (unsigned int*)alloc(sizeof(unsigned int) * (size_t)N);
    float4* boxes = (float4*)alloc(sizeof(float4) * (size_t)N);
    char* zero_base = base + off;
    unsigned int* hist = (unsigned int*)alloc(65536 * sizeof(unsigned int));
    SelState* state = (SelState*)alloc(256);
    unsigned int* counter = (unsigned int*)alloc(256);
    unsigned long long* valid_words = (unsigned long long*)alloc(128 * 8);
    unsigned long long* sel = (unsigned long long*)alloc(sizeof(unsigned long long) * SELCAP);
    size_t zero_sz = (size_t)((base + off) - zero_base);
    float4* boxes_sorted = (float4*)alloc(sizeof(float4) * 6016);
    unsigned long long* mask = (unsigned long long*)alloc(sizeof(unsigned long long) * (size_t)N_PRE * NW);

    hipMemsetAsync(zero_base, 0, zero_sz, stream);

    int nb = (N + 255) / 256;
    decode_kernel<<<nb, 256, 0, stream>>>(deltas, anchors, scores, ph, pw, ps,
                                          s32buf, boxes, hist, N);
    pick_pass<<<1, 1024, 0, stream>>>(hist, state);
    compact_kernel<<<nb, 256, 0, stream>>>(s32buf, state, sel, counter, N);
    rank_scatter<<<RS_BLK, 256, 0, stream>>>(sel, boxes, boxes_sorted, valid_words, N);
    mask_kernel<<<dim3(NW, NW), 64, 0, stream>>>(boxes_sorted, mask);
    nms_seq<<<1, 64, 0, stream>>>(mask, valid_words, boxes_sorted, (float*)d_out);
}

// Round 6
// 290.589 us; speedup vs baseline: 2.1046x; 1.3710x over previous
//
#include <hip/hip_runtime.h>

#pragma clang fp contract(off)

#define N_PRE   6000
#define N_POST  300
#define NW      94          // 64-bit words per mask row (ceil(6000/64))
#define SELCAP  7936        // 124*64 pool capacity (top-6000 + digit-bucket ties)
#define RS_BLK  124
#define NBIN    16384       // 14-bit digit histogram
#define DSHIFT  18          // digit = s32 >> 18
#define HPART   64          // partial histogram copies

struct SelState {
    unsigned int thr;       // 14-bit digit threshold: keep if (s32>>DSHIFT) >= thr
};

// ---------------------------------------------------------------------------
// 1. decode + clip + valid + sortable 32-bit score key (pure streaming).
// Blocks 0/1 also zero sel / valid_words / counter (replaces memset node).
// full key (built in compact) = (s32 << 32) | ~index -> distinct; descending
// score, ascending index tie-break == jax.lax.top_k stable order.
// ---------------------------------------------------------------------------
__global__ void decode_kernel(const float4* __restrict__ deltas,
                              const float4* __restrict__ anchors,
                              const float*  __restrict__ scores,
                              const int* __restrict__ ph, const int* __restrict__ pw,
                              const int* __restrict__ ps,
                              unsigned int* __restrict__ s32out,
                              float4* __restrict__ boxes,
                              unsigned long long* __restrict__ sel,
                              unsigned long long* __restrict__ valid_words,
                              unsigned int* __restrict__ counter, int N)
{
#pragma clang fp contract(off)
    if (blockIdx.x == 0) {
        for (int t = threadIdx.x; t < SELCAP; t += 256) sel[t] = 0ull;
    } else if (blockIdx.x == 1) {
        if (threadIdx.x < 128) valid_words[threadIdx.x] = 0ull;
        if (threadIdx.x == 0) *counter = 0u;
    }
    int i = blockIdx.x * blockDim.x + threadIdx.x;
    if (i >= N) return;
    float H = (float)(*ph), W = (float)(*pw), S = (float)(*ps);
    float4 d = deltas[i];
    float4 a = anchors[i];
    float h = a.z - a.x, w = a.w - a.y;
    float cy = a.x + 0.5f * h, cx = a.y + 0.5f * w;
    float ncy = d.x * h + cy;
    float ncx = d.y * w + cx;
    float eh = (float)exp((double)d.z);   // correctly-rounded f32 exp
    float ew = (float)exp((double)d.w);
    float nh = eh * h;
    float nw = ew * w;
    float ymin = ncy - 0.5f * nh, xmin = ncx - 0.5f * nw;
    float ymax = ncy + 0.5f * nh, xmax = ncx + 0.5f * nw;
    ymin = fminf(fmaxf(ymin, 0.0f), H);
    xmin = fminf(fmaxf(xmin, 0.0f), W);
    ymax = fminf(fmaxf(ymax, 0.0f), H);
    xmax = fminf(fmaxf(xmax, 0.0f), W);
    bool valid = (ymax - ymin >= S) && (xmax - xmin >= S);
    float sc = scores[i];
    unsigned int bits = __float_as_uint(sc);
    unsigned int s32;
    if (!valid) s32 = 0x007FFFFFu;   // sortable encoding of -inf
    else        s32 = (bits & 0x80000000u) ? ~bits : (bits | 0x80000000u);
    s32out[i] = s32;
    boxes[i]  = make_float4(ymin, xmin, ymax, xmax);
}

// ---------------------------------------------------------------------------
// 2a. LDS-privatized partial histograms (no global atomics)
// ---------------------------------------------------------------------------
__global__ __launch_bounds__(256) void hist_part(const unsigned int* __restrict__ s32in,
                                                 unsigned int* __restrict__ phist, int N)
{
    __shared__ unsigned int lh[NBIN];   // 64 KiB
    int tid = threadIdx.x;
    for (int j = tid; j < NBIN; j += 256) lh[j] = 0u;
    __syncthreads();
    for (int i = blockIdx.x * 256 + tid; i < N; i += HPART * 256)
        atomicAdd(&lh[s32in[i] >> DSHIFT], 1u);
    __syncthreads();
    unsigned int* dst = phist + blockIdx.x * NBIN;
    for (int j = tid; j < NBIN; j += 256) dst[j] = lh[j];
}

// ---------------------------------------------------------------------------
// 2b. reduce partials -> hist (atomic-free, coalesced)
// ---------------------------------------------------------------------------
__global__ __launch_bounds__(256) void hist_reduce(const unsigned int* __restrict__ phist,
                                                   unsigned int* __restrict__ hist)
{
    int j = blockIdx.x * 256 + threadIdx.x;   // NBIN/256 = 64 blocks
    unsigned int s = 0;
#pragma unroll 8
    for (int b = 0; b < HPART; b++) s += phist[b * NBIN + j];
    hist[j] = s;
}

// ---------------------------------------------------------------------------
// 3. pick: thr = max 14-bit digit with suffix-count(>= thr) >= 6000
// ---------------------------------------------------------------------------
__global__ __launch_bounds__(1024) void pick_pass(const unsigned int* __restrict__ hist,
                                                  SelState* __restrict__ state)
{
    __shared__ unsigned int wsum[16];
    __shared__ int sel_chunk;
    __shared__ unsigned int sel_above;
    int tid = threadIdx.x, lane = tid & 63, wave = tid >> 6;
    const unsigned int k = 6000u;

    unsigned int s = 0;
    int base = tid * 16;
#pragma unroll
    for (int i = 0; i < 16; i++) s += hist[base + i];
    // inclusive suffix scan over 1024 chunk sums (wave scan + wave totals)
    unsigned int S = s;
    for (int d = 1; d < 64; d <<= 1) {
        unsigned int t = __shfl_down(S, d);
        if (lane + d < 64) S += t;
    }
    if (lane == 0) wsum[wave] = S;
    __syncthreads();
    unsigned int above = 0;
    for (int w2 = wave + 1; w2 < 16; w2++) above += wsum[w2];
    unsigned int F  = S + above;   // suffix including chunk tid
    unsigned int Fn = F - s;       // suffix excluding chunk tid
    if (Fn < k && k <= F) { sel_chunk = tid; sel_above = Fn; }
    __syncthreads();
    int c = sel_chunk;
    unsigned int acc = sel_above;
    if (wave == 0 && lane < 16) {
        unsigned int b = hist[c * 16 + lane];
        unsigned int B = b;
        for (int d = 1; d < 16; d <<= 1) {
            unsigned int t = __shfl_down(B, d);
            if (lane + d < 16) B += t;
        }
        unsigned int Bn = B - b;
        unsigned int kk = k - acc;
        if (Bn < kk && kk <= B) state->thr = (unsigned int)(c * 16 + lane);
    }
}

// ---------------------------------------------------------------------------
// 4. compact: pool = all elements whose 14-bit digit >= thr (>=6000, <=cap)
// ---------------------------------------------------------------------------
__global__ void compact_kernel(const unsigned int* __restrict__ s32in,
                               const SelState* __restrict__ state,
                               unsigned long long* __restrict__ sel,
                               unsigned int* __restrict__ counter, int N)
{
    int i = blockIdx.x * blockDim.x + threadIdx.x;
    if (i >= N) return;
    unsigned int s32 = s32in[i];
    if ((s32 >> DSHIFT) >= state->thr) {
        unsigned int p = atomicAdd(counter, 1u);
        if (p < SELCAP)
            sel[p] = ((unsigned long long)s32 << 32) |
                     (unsigned long long)(~(unsigned int)i);
    }
}

// ---------------------------------------------------------------------------
// 5. exact rank by count over full 64-bit keys; scatter boxes + valid bits
// ---------------------------------------------------------------------------
__global__ __launch_bounds__(256) void rank_scatter(
    const unsigned long long* __restrict__ sel,   // SELCAP entries, zero-padded
    const float4* __restrict__ boxes,
    float4* __restrict__ boxes_sorted,
    unsigned long long* __restrict__ valid_words, int N)
{
    __shared__ __align__(16) unsigned long long kbuf[SELCAP];   // 62 KiB
    __shared__ unsigned int cnt4[4][64];
    int tid = threadIdx.x;
    for (int t = tid; t < SELCAP; t += 256) kbuf[t] = sel[t];
    __syncthreads();
    int lane = tid & 63;
    int slice = tid >> 6;                 // 0..3
    int i = blockIdx.x * 64 + lane;       // my key slot
    unsigned long long my = kbuf[i];
    const int SL = SELCAP / 4;            // 1984
    int j0 = slice * SL;
    unsigned int c = 0;
#pragma unroll 8
    for (int j = j0; j < j0 + SL; j += 2) {
        ulonglong2 kk = *reinterpret_cast<const ulonglong2*>(&kbuf[j]);
        c += (kk.x > my) || (kk.x == my && j < i);
        c += (kk.y > my) || (kk.y == my && (j + 1) < i);
    }
    cnt4[slice][lane] = c;
    __syncthreads();
    if (tid < 64) {
        unsigned int rank = cnt4[0][tid] + cnt4[1][tid] + cnt4[2][tid] + cnt4[3][tid];
        unsigned long long key = kbuf[blockIdx.x * 64 + tid];
        if (key != 0ull && rank < N_PRE) {
            unsigned int s32 = (unsigned int)(key >> 32);
            unsigned int ii  = ~(unsigned int)(key & 0xFFFFFFFFull);
            float4 b = (ii < (unsigned int)N) ? boxes[ii] : make_float4(0.f,0.f,0.f,0.f);
            boxes_sorted[rank] = b;
            bool v = (s32 != 0x007FFFFFu) && (ii < (unsigned int)N);
            if (v) atomicOr(&valid_words[rank >> 6], 1ull << (rank & 63));
        }
    }
}

// ---------------------------------------------------------------------------
// 6. pairwise suppression mask, upper triangle only (incl. diagonal word)
// ---------------------------------------------------------------------------
__global__ __launch_bounds__(64) void mask_kernel(const float4* __restrict__ boxes_sorted,
                                                  unsigned long long* __restrict__ mask)
{
#pragma clang fp contract(off)
    int rb = blockIdx.y, cb = blockIdx.x;
    if (cb < rb) return;
    __shared__ float4 cbox[64];
    int tid = threadIdx.x;
    int col0 = cb * 64;
    int c = col0 + tid;
    cbox[tid] = (c < N_PRE) ? boxes_sorted[c] : make_float4(0.f, 0.f, 0.f, 0.f);
    __syncthreads();
    int i = rb * 64 + tid;
    if (i >= N_PRE) return;
    float4 bi = boxes_sorted[i];
    float area_i = (bi.z - bi.x) * (bi.w - bi.y);
    unsigned long long word = 0ull;
#pragma unroll 8
    for (int j = 0; j < 64; j++) {
        float4 bj = cbox[j];
        float iy = fminf(bi.z, bj.z) - fmaxf(bi.x, bj.x);
        iy = fmaxf(iy, 0.0f);
        float ix = fminf(bi.w, bj.w) - fmaxf(bi.y, bj.y);
        ix = fmaxf(ix, 0.0f);
        float inter = iy * ix;
        float area_j = (bj.z - bj.x) * (bj.w - bj.y);
        float iou = inter / (((area_i + area_j) - inter) + 1e-9f);
        if ((col0 + j) > i && iou > 0.7f) word |= (1ull << j);
    }
    mask[(size_t)i * NW + cb] = word;
}

// ---------------------------------------------------------------------------
// 7. word-sequential greedy NMS, single wave, zero LDS:
//    removed[] words live in registers (lane l owns word l and word 64+l),
//    current word broadcast via shfl; keeps resolved by ballot-IoU;
//    mask-row ORs batched 4-wide so each word pays ~one memory latency.
// ---------------------------------------------------------------------------
__global__ __launch_bounds__(64) void nms_seq(const unsigned long long* __restrict__ mask,
                                              const unsigned long long* __restrict__ valid_words,
                                              const float4* __restrict__ boxes_sorted,
                                              float* __restrict__ out)
{
#pragma clang fp contract(off)
    int lane = threadIdx.x;
    float4* out4 = reinterpret_cast<float4*>(out);

    // zero output
    for (int t = lane; t < N_POST; t += 64)
        out4[t] = make_float4(0.f, 0.f, 0.f, 0.f);

    // removed-words in registers; pad bits of word 93 are 0 in valid_words
    unsigned long long rem0 = ~valid_words[lane];
    unsigned long long rem1 = ~((lane < NW - 64) ? valid_words[64 + lane] : 0ull);

    int rank = 0;
    float4 cb = boxes_sorted[lane];          // word 0 boxes
    for (int w = 0; w < NW; w++) {
        // prefetch next word's boxes
        float4 nb;
        if (w < NW - 1) nb = boxes_sorted[(w + 1) * 64 + lane];

        // broadcast removed word w from its owner lane
        unsigned long long remw = (w < 64) ? __shfl(rem0, w) : __shfl(rem1, w - 64);
        unsigned long long aw = ~remw;

        unsigned long long keptb = 0ull;
        if (aw) {
            float area_me = (cb.z - cb.x) * (cb.w - cb.y);
            while (aw) {
                int b = __builtin_ctzll(aw);     // wave-uniform
                float kx = __shfl(cb.x, b);
                float ky = __shfl(cb.y, b);
                float kz = __shfl(cb.z, b);
                float kw = __shfl(cb.w, b);
                float iy = fmaxf(fminf(cb.z, kz) - fmaxf(cb.x, kx), 0.0f);
                float ix = fmaxf(fminf(cb.w, kw) - fmaxf(cb.y, ky), 0.0f);
                float inter = iy * ix;
                float ka = (kz - kx) * (kw - ky);
                float iou = inter / (((area_me + ka) - inter) + 1e-9f);
                unsigned long long sup = __ballot(iou > 0.7f);
                if (lane == b) out4[rank] = cb;
                keptb |= (1ull << b);
                rank++;
                aw &= ~(sup | (1ull << b));
                if (rank >= N_POST) break;
            }
        }

        if (rank >= N_POST) break;

        // apply mask rows of this word's keeps (4-wide independent loads)
        unsigned long long kb = keptb;
        while (kb) {
            int b0 = __builtin_ctzll(kb); kb &= kb - 1ull;
            int b1 = -1, b2 = -1, b3 = -1;
            if (kb) { b1 = __builtin_ctzll(kb); kb &= kb - 1ull; }
            if (kb) { b2 = __builtin_ctzll(kb); kb &= kb - 1ull; }
            if (kb) { b3 = __builtin_ctzll(kb); kb &= kb - 1ull; }
            const unsigned long long* p0 = mask + (size_t)(w * 64 + b0) * NW;
            unsigned long long l0 = p0[lane];
            unsigned long long h0 = (lane < NW - 64) ? p0[64 + lane] : 0ull;
            unsigned long long l1 = 0, h1 = 0, l2 = 0, h2 = 0, l3 = 0, h3 = 0;
            if (b1 >= 0) {
                const unsigned long long* p1 = mask + (size_t)(w * 64 + b1) * NW;
                l1 = p1[lane];
                h1 = (lane < NW - 64) ? p1[64 + lane] : 0ull;
            }
            if (b2 >= 0) {
                const unsigned long long* p2 = mask + (size_t)(w * 64 + b2) * NW;
                l2 = p2[lane];
                h2 = (lane < NW - 64) ? p2[64 + lane] : 0ull;
            }
            if (b3 >= 0) {
                const unsigned long long* p3 = mask + (size_t)(w * 64 + b3) * NW;
                l3 = p3[lane];
                h3 = (lane < NW - 64) ? p3[64 + lane] : 0ull;
            }
            // garbage in words < w is harmless: those words are never revisited
            rem0 |= (l0 | l1) | (l2 | l3);
            rem1 |= (h0 | h1) | (h2 | h3);
        }

        cb = nb;
    }
}

// ---------------------------------------------------------------------------
extern "C" void kernel_launch(void* const* d_in, const int* in_sizes, int n_in,
                              void* d_out, int out_size, void* d_ws, size_t ws_size,
                              hipStream_t stream)
{
    const float4* deltas  = (const float4*)d_in[0];
    const float4* anchors = (const float4*)d_in[1];
    const float*  scores  = (const float*)d_in[2];
    const int* ph = (const int*)d_in[3];
    const int* pw = (const int*)d_in[4];
    const int* ps = (const int*)d_in[5];
    int N = in_sizes[2];

    char* base = (char*)d_ws;
    size_t off = 0;
    auto alloc = [&](size_t sz) -> void* {
        void* p = base + off;
        off = (off + sz + 255) & ~(size_t)255;
        return p;
    };
    unsigned int* s32buf = (unsigned int*)alloc(sizeof(unsigned int) * (size_t)N);
    float4* boxes = (float4*)alloc(sizeof(float4) * (size_t)N);
    unsigned int* phist = (unsigned int*)alloc((size_t)HPART * NBIN * sizeof(unsigned int));
    unsigned int* hist = (unsigned int*)alloc(NBIN * sizeof(unsigned int));
    SelState* state = (SelState*)alloc(256);
    unsigned int* counter = (unsigned int*)alloc(256);
    unsigned long long* valid_words = (unsigned long long*)alloc(128 * 8);
    unsigned long long* sel = (unsigned long long*)alloc(sizeof(unsigned long long) * SELCAP);
    float4* boxes_sorted = (float4*)alloc(sizeof(float4) * 6016);
    unsigned long long* mask = (unsigned long long*)alloc(sizeof(unsigned long long) * (size_t)N_PRE * NW);

    int nb = (N + 255) / 256;
    decode_kernel<<<nb, 256, 0, stream>>>(deltas, anchors, scores, ph, pw, ps,
                                          s32buf, boxes, sel, valid_words, counter, N);
    hist_part<<<HPART, 256, 0, stream>>>(s32buf, phist, N);
    hist_reduce<<<NBIN / 256, 256, 0, stream>>>(phist, hist);
    pick_pass<<<1, 1024, 0, stream>>>(hist, state);
    compact_kernel<<<nb, 256, 0, stream>>>(s32buf, state, sel, counter, N);
    rank_scatter<<<RS_BLK, 256, 0, stream>>>(sel, boxes, boxes_sorted, valid_words, N);
    mask_kernel<<<dim3(NW, NW), 64, 0, stream>>>(boxes_sorted, mask);
    nms_seq<<<1, 64, 0, stream>>>(mask, valid_words, boxes_sorted, (float*)d_out);
}